// Round 3
// baseline (1946.146 us; speedup 1.0000x reference)
//
#include <hip/hip_runtime.h>

// LatticeSuperpixel: B=8, C=20, H=W=512, 32x32 seeds, 16x16 cells, 4 levels.
#define NB 8
#define NC 20
#define NH 512
#define NW 512
#define NS 1024           // 32*32 seeds
#define HW (NH * NW)
#define SEEDS_ELEMS (NB * NS * NC)   // 163840
#define DENOM_ELEMS (NB * NS)        // 8192

__device__ __forceinline__ int clampi(int v, int lo, int hi) {
    return v < lo ? lo : (v > hi ? hi : v);
}

__constant__ int c_dyo[9] = {-1, -1, -1, 0, 0, 0, 1, 1, 1};
__constant__ int c_dxo[9] = {-1, 0, 1, -1, 0, 1, -1, 0, 1};

// ---------------------------------------------------------------------------
// Kernel 1: seed init = mean over each 16x16 patch, per channel.
// 160 threads: (c in 0..19, s in 0..7); thread sums 8 float4 pixel-quads.
// ---------------------------------------------------------------------------
__global__ __launch_bounds__(160) void k_seed_init(const float* __restrict__ x,
                                                   float* __restrict__ seeds) {
    const int tt = threadIdx.x;           // < 160
    const int cell = blockIdx.x;
    const int b = blockIdx.y;
    const int cy = cell >> 5, cx = cell & 31;
    const int c = tt >> 3, s = tt & 7;

    const float* xb = x + (size_t)b * (NC * HW) + (size_t)c * HW
                        + (size_t)(cy << 4) * NW + (cx << 4);
    float acc = 0.f;
#pragma unroll
    for (int k = 0; k < 8; ++k) {
        const int row = (k << 1) + (s >> 2);
        const int col = (s & 3) << 2;
        const float4 v = *reinterpret_cast<const float4*>(xb + row * NW + col);
        acc += v.x + v.y + v.z + v.w;
    }
    acc += __shfl_xor(acc, 1, 64);
    acc += __shfl_xor(acc, 2, 64);
    acc += __shfl_xor(acc, 4, 64);
    if (s == 0)
        seeds[((size_t)(b << 10) + cell) * NC + c] = acc * (1.0f / 256.0f);
}

// ---------------------------------------------------------------------------
// Kernel 2: one assignment iteration + seed-update accumulation.
// Phase 1 (256 thr = 1 pixel each): dist vs 9 neighbor seeds, softmax -> qs_t.
// Phase 2 (168 thr = (c in 0..20, s in 0..7)): scalar acc[9] per worker;
//   q quads from LDS (broadcast, conflict-free), x quads re-read from L1-hot
//   global; strip-fold via shfl_xor (s = lane bits 0..2); 189 atomics/block.
// ---------------------------------------------------------------------------
__global__ __launch_bounds__(256, 5) void k_iter(const float* __restrict__ x,
                                                 const float* __restrict__ seeds,
                                                 float* __restrict__ numer,
                                                 float* __restrict__ denom) {
    __shared__ float s_lds[9][NC];
    __shared__ float s_sn[9];
    __shared__ __align__(16) float qs_t[9][260];   // row stride 1040 B (16B-aligned)

    const int t = threadIdx.x;
    const int cell = blockIdx.x;
    const int b = blockIdx.y;
    const int cy = cell >> 5, cx = cell & 31;

    // ---- phase 1: per-pixel distances + softmax ----
    const int py = (cy << 4) + (t >> 4);
    const int px = (cx << 4) + (t & 15);
    const float* xp = x + (size_t)b * (NC * HW) + (size_t)py * NW + px;
    float xv[NC];
#pragma unroll
    for (int c = 0; c < NC; ++c) xv[c] = xp[(size_t)c * HW];

    if (t < 180) {
        const int o = t / 20, c = t - o * 20;
        const int ny = clampi(cy + c_dyo[o], 0, 31);
        const int nx = clampi(cx + c_dxo[o], 0, 31);
        s_lds[o][c] = seeds[((size_t)(b << 10) + (ny << 5) + nx) * NC + c];
    }
    __syncthreads();
    if (t < 9) {
        float s = 0.f;
#pragma unroll
        for (int c = 0; c < NC; ++c) s += s_lds[t][c] * s_lds[t][c];
        s_sn[t] = s;
    }
    __syncthreads();

    float d[9];
#pragma unroll
    for (int o = 0; o < 9; ++o) {
        float ip = 0.f;
#pragma unroll
        for (int c = 0; c < NC; ++c) ip += xv[c] * s_lds[o][c];
        d[o] = s_sn[o] - 2.0f * ip;
    }
    float m = d[0];
#pragma unroll
    for (int o = 1; o < 9; ++o) m = fminf(m, d[o]);
    float w[9];
    float wsum = 0.f;
#pragma unroll
    for (int o = 0; o < 9; ++o) {
        w[o] = __expf(m - d[o]);
        wsum += w[o];
    }
    const float inv = 1.0f / wsum;
#pragma unroll
    for (int o = 0; o < 9; ++o) qs_t[o][t] = w[o] * inv;  // bank (4o+t)%32: 2-way, free
    __syncthreads();

    // ---- phase 2: scalar acc[9] per (c,s); quads qd = 8k+s ----
    if (t < 168) {
        const int c = t >> 3, s = t & 7;   // c in 0..20 (20 == denom channel)
        float acc[9];
#pragma unroll
        for (int o = 0; o < 9; ++o) acc[o] = 0.f;

        const float* xb = x + (size_t)b * (NC * HW) + (size_t)c * HW
                            + (size_t)(cy << 4) * NW + (cx << 4);
        const int row0 = s >> 2, col = (s & 3) << 2;
#pragma unroll
        for (int k = 0; k < 8; ++k) {
            const int qd = (k << 3) + s;          // pixel-quad id
            float4 f4;
            if (c < NC) {
                f4 = *reinterpret_cast<const float4*>(xb + ((k << 1) + row0) * NW + col);
            } else {
                f4 = make_float4(1.f, 1.f, 1.f, 1.f);
            }
#pragma unroll
            for (int o = 0; o < 9; ++o) {
                // lanes' s=0..7 span banks 0..31 once; c-lanes broadcast: free
                const float4 q4 = *reinterpret_cast<const float4*>(&qs_t[o][qd << 2]);
                acc[o] += q4.x * f4.x + q4.y * f4.y + q4.z * f4.z + q4.w * f4.w;
            }
        }
        // fold the 8 strips (s = lane bits 0..2, partners stay in-octet)
#pragma unroll
        for (int o = 0; o < 9; ++o) {
            acc[o] += __shfl_xor(acc[o], 1, 64);
            acc[o] += __shfl_xor(acc[o], 2, 64);
            acc[o] += __shfl_xor(acc[o], 4, 64);
        }
        if (s == 0) {
            const size_t sb = (size_t)(b << 10);
#pragma unroll
            for (int o = 0; o < 9; ++o) {
                const int ny = clampi(cy + c_dyo[o], 0, 31);
                const int nx = clampi(cx + c_dxo[o], 0, 31);
                const size_t sidx = sb + (ny << 5) + nx;
                if (c < NC) atomicAdd(&numer[sidx * NC + c], acc[o]);
                else        atomicAdd(&denom[sidx], acc[o]);
            }
        }
    }
}

// ---------------------------------------------------------------------------
// Kernel 3: seeds = numer / (denom + eps)
// ---------------------------------------------------------------------------
__global__ __launch_bounds__(256) void k_div(float* __restrict__ seeds,
                                             const float* __restrict__ numer,
                                             const float* __restrict__ denom) {
    const int i = blockIdx.x * 256 + threadIdx.x;  // < 163840
    seeds[i] = numer[i] / (denom[i / NC] + 1e-8f);
}

// ---------------------------------------------------------------------------
// Kernel 4: final assignment pass -> write Q (B, 9, H, W)
// ---------------------------------------------------------------------------
__global__ __launch_bounds__(256) void k_final(const float* __restrict__ x,
                                               const float* __restrict__ seeds,
                                               float* __restrict__ out) {
    __shared__ float s_lds[9][NC];
    __shared__ float s_sn[9];

    const int t = threadIdx.x;
    const int cell = blockIdx.x;
    const int b = blockIdx.y;
    const int cy = cell >> 5, cx = cell & 31;

    const int py = (cy << 4) + (t >> 4);
    const int px = (cx << 4) + (t & 15);
    const float* xp = x + (size_t)b * (NC * HW) + (size_t)py * NW + px;
    float xv[NC];
#pragma unroll
    for (int c = 0; c < NC; ++c) xv[c] = xp[(size_t)c * HW];

    if (t < 180) {
        const int o = t / 20, c = t - o * 20;
        const int ny = clampi(cy + c_dyo[o], 0, 31);
        const int nx = clampi(cx + c_dxo[o], 0, 31);
        s_lds[o][c] = seeds[((size_t)(b << 10) + (ny << 5) + nx) * NC + c];
    }
    __syncthreads();
    if (t < 9) {
        float s = 0.f;
#pragma unroll
        for (int c = 0; c < NC; ++c) s += s_lds[t][c] * s_lds[t][c];
        s_sn[t] = s;
    }
    __syncthreads();

    float d[9];
#pragma unroll
    for (int o = 0; o < 9; ++o) {
        float ip = 0.f;
#pragma unroll
        for (int c = 0; c < NC; ++c) ip += xv[c] * s_lds[o][c];
        d[o] = s_sn[o] - 2.0f * ip;
    }
    float m = d[0];
#pragma unroll
    for (int o = 1; o < 9; ++o) m = fminf(m, d[o]);
    float w[9];
    float wsum = 0.f;
#pragma unroll
    for (int o = 0; o < 9; ++o) {
        w[o] = __expf(m - d[o]);
        wsum += w[o];
    }
    const float inv = 1.0f / wsum;
#pragma unroll
    for (int o = 0; o < 9; ++o) {
        out[(((size_t)b * 9 + o) * NH + py) * NW + px] = w[o] * inv;
    }
}

// ---------------------------------------------------------------------------
extern "C" void kernel_launch(void* const* d_in, const int* in_sizes, int n_in,
                              void* d_out, int out_size, void* d_ws, size_t ws_size,
                              hipStream_t stream) {
    const float* x = (const float*)d_in[0];
    float* out = (float*)d_out;

    float* seeds = (float*)d_ws;                 // 163840 floats
    float* numer = seeds + SEEDS_ELEMS;          // 163840 floats
    float* denom = numer + SEEDS_ELEMS;          // 8192 floats

    const dim3 grid(NS, NB);  // 1024 cells x 8 batches
    k_seed_init<<<grid, 160, 0, stream>>>(x, seeds);

    for (int it = 0; it < 3; ++it) {
        hipMemsetAsync(numer, 0, (SEEDS_ELEMS + DENOM_ELEMS) * sizeof(float), stream);
        k_iter<<<grid, 256, 0, stream>>>(x, seeds, numer, denom);
        k_div<<<SEEDS_ELEMS / 256, 256, 0, stream>>>(seeds, numer, denom);
    }
    k_final<<<grid, 256, 0, stream>>>(x, seeds, out);
}

// Round 4
// 554.688 us; speedup vs baseline: 3.5085x; 3.5085x over previous
//
#include <hip/hip_runtime.h>

// LatticeSuperpixel: B=8, C=20, H=W=512, 32x32 seeds, 16x16 cells, 4 levels.
#define NB 8
#define NC 20
#define NH 512
#define NW 512
#define NS 1024           // 32*32 seeds
#define HW (NH * NW)
#define SEEDS_ELEMS (NB * NS * NC)   // 163840
#define DENOM_ELEMS (NB * NS)        // 8192

__device__ __forceinline__ int clampi(int v, int lo, int hi) {
    return v < lo ? lo : (v > hi ? hi : v);
}

__constant__ int c_dyo[9] = {-1, -1, -1, 0, 0, 0, 1, 1, 1};
__constant__ int c_dxo[9] = {-1, 0, 1, -1, 0, 1, -1, 0, 1};

// ---------------------------------------------------------------------------
// Kernel 1: seed init = mean over each 16x16 patch, per channel.
// ---------------------------------------------------------------------------
__global__ __launch_bounds__(160) void k_seed_init(const float* __restrict__ x,
                                                   float* __restrict__ seeds) {
    const int tt = threadIdx.x;           // < 160
    const int cell = blockIdx.x;
    const int b = blockIdx.y;
    const int cy = cell >> 5, cx = cell & 31;
    const int c = tt >> 3, s = tt & 7;

    const float* xb = x + (size_t)b * (NC * HW) + (size_t)c * HW
                        + (size_t)(cy << 4) * NW + (cx << 4);
    float acc = 0.f;
#pragma unroll
    for (int k = 0; k < 8; ++k) {
        const int row = (k << 1) + (s >> 2);
        const int col = (s & 3) << 2;
        const float4 v = *reinterpret_cast<const float4*>(xb + row * NW + col);
        acc += v.x + v.y + v.z + v.w;
    }
    acc += __shfl_xor(acc, 1, 64);
    acc += __shfl_xor(acc, 2, 64);
    acc += __shfl_xor(acc, 4, 64);
    if (s == 0)
        seeds[((size_t)(b << 10) + cell) * NC + c] = acc * (1.0f / 256.0f);
}

// ---------------------------------------------------------------------------
// Kernel 2: one assignment iteration + seed-update accumulation.
// Stage:   x tile -> LDS transposed (5 float4 loads/thread, coalesced).
// Phase 1: 256 thr = 1 pixel: dist vs 9 seeds (b128 seed rows), softmax->qs_t.
// Phase 2: 168 thr = (c in 0..20, s in 0..7): offsets in 3 batches of 3
//          (acc[3] keeps VGPR low); q + x both from LDS, conflict-free;
//          strip-fold via shfl_xor; 189 atomics/block.
// ---------------------------------------------------------------------------
__global__ __launch_bounds__(256, 4) void k_iter(const float* __restrict__ x,
                                                 const float* __restrict__ seeds,
                                                 float* __restrict__ numer,
                                                 float* __restrict__ denom) {
    __shared__ __align__(16) float xs_t[NC][260];  // [channel][pixel] 20.8 KB
    __shared__ __align__(16) float qs_t[9][260];   // [offset][pixel]   9.4 KB
    __shared__ __align__(16) float s_lds[9][24];   // seed rows, b128-readable
    __shared__ float s_sn[9];

    const int t = threadIdx.x;
    const int cell = blockIdx.x;
    const int b = blockIdx.y;
    const int cy = cell >> 5, cx = cell & 31;

    // ---- stage x tile into LDS (channel-major) ----
    const float* xb = x + (size_t)b * (NC * HW) + (size_t)(cy << 4) * NW + (cx << 4);
#pragma unroll
    for (int j = 0; j < 5; ++j) {
        const int Lq = (j << 8) + t;          // linear quad id: c*64 + qd
        const int c = Lq >> 6, qd = Lq & 63;  // qd -> row=qd>>2, colq=qd&3
        const float4 v = *reinterpret_cast<const float4*>(
            xb + (size_t)c * HW + (qd >> 2) * NW + ((qd & 3) << 2));
        *reinterpret_cast<float4*>(&xs_t[c][qd << 2]) = v;
    }
    // ---- stage 9 neighbor seeds ----
    if (t < 180) {
        const int o = t / 20, c = t - o * 20;
        const int ny = clampi(cy + c_dyo[o], 0, 31);
        const int nx = clampi(cx + c_dxo[o], 0, 31);
        s_lds[o][c] = seeds[((size_t)(b << 10) + (ny << 5) + nx) * NC + c];
    }
    __syncthreads();
    if (t < 9) {
        float s = 0.f;
#pragma unroll
        for (int c = 0; c < NC; ++c) s += s_lds[t][c] * s_lds[t][c];
        s_sn[t] = s;
    }
    __syncthreads();

    // ---- phase 1: per-pixel distances + softmax ----
    float xv[NC];
#pragma unroll
    for (int c = 0; c < NC; ++c) xv[c] = xs_t[c][t];

    float d[9];
#pragma unroll
    for (int o = 0; o < 9; ++o) {
        float ip = 0.f;
#pragma unroll
        for (int j = 0; j < 5; ++j) {
            const float4 s4 = *reinterpret_cast<const float4*>(&s_lds[o][j << 2]);
            ip += xv[(j << 2) + 0] * s4.x + xv[(j << 2) + 1] * s4.y
                + xv[(j << 2) + 2] * s4.z + xv[(j << 2) + 3] * s4.w;
        }
        d[o] = s_sn[o] - 2.0f * ip;
    }
    float m = d[0];
#pragma unroll
    for (int o = 1; o < 9; ++o) m = fminf(m, d[o]);
    float w[9];
    float wsum = 0.f;
#pragma unroll
    for (int o = 0; o < 9; ++o) {
        w[o] = __expf(m - d[o]);
        wsum += w[o];
    }
    const float inv = 1.0f / wsum;
#pragma unroll
    for (int o = 0; o < 9; ++o) qs_t[o][t] = w[o] * inv;
    __syncthreads();

    // ---- phase 2: 3 offset-batches of 3, acc in registers ----
    if (t < 168) {
        const int c = t >> 3, s = t & 7;   // c in 0..20 (20 == denom channel)
        const size_t sb = (size_t)(b << 10);
#pragma unroll
        for (int ob = 0; ob < 3; ++ob) {
            float acc[3] = {0.f, 0.f, 0.f};
#pragma unroll 2
            for (int k = 0; k < 8; ++k) {
                const int qd = (k << 3) + s;
                float4 f4;
                if (c < NC) f4 = *reinterpret_cast<const float4*>(&xs_t[c][qd << 2]);
                else        f4 = make_float4(1.f, 1.f, 1.f, 1.f);
#pragma unroll
                for (int oo = 0; oo < 3; ++oo) {
                    const float4 q4 = *reinterpret_cast<const float4*>(
                        &qs_t[ob * 3 + oo][qd << 2]);
                    acc[oo] += q4.x * f4.x + q4.y * f4.y + q4.z * f4.z + q4.w * f4.w;
                }
            }
            // fold the 8 strips (s = lane bits 0..2)
#pragma unroll
            for (int oo = 0; oo < 3; ++oo) {
                acc[oo] += __shfl_xor(acc[oo], 1, 64);
                acc[oo] += __shfl_xor(acc[oo], 2, 64);
                acc[oo] += __shfl_xor(acc[oo], 4, 64);
            }
            if (s == 0) {
#pragma unroll
                for (int oo = 0; oo < 3; ++oo) {
                    const int o = ob * 3 + oo;
                    const int ny = clampi(cy + c_dyo[o], 0, 31);
                    const int nx = clampi(cx + c_dxo[o], 0, 31);
                    const size_t sidx = sb + (ny << 5) + nx;
                    if (c < NC) atomicAdd(&numer[sidx * NC + c], acc[oo]);
                    else        atomicAdd(&denom[sidx], acc[oo]);
                }
            }
        }
    }
}

// ---------------------------------------------------------------------------
// Kernel 3: seeds = numer / (denom + eps)
// ---------------------------------------------------------------------------
__global__ __launch_bounds__(256) void k_div(float* __restrict__ seeds,
                                             const float* __restrict__ numer,
                                             const float* __restrict__ denom) {
    const int i = blockIdx.x * 256 + threadIdx.x;  // < 163840
    seeds[i] = numer[i] / (denom[i / NC] + 1e-8f);
}

// ---------------------------------------------------------------------------
// Kernel 4: final assignment pass -> write Q (B, 9, H, W)
// ---------------------------------------------------------------------------
__global__ __launch_bounds__(256) void k_final(const float* __restrict__ x,
                                               const float* __restrict__ seeds,
                                               float* __restrict__ out) {
    __shared__ __align__(16) float s_lds[9][24];
    __shared__ float s_sn[9];

    const int t = threadIdx.x;
    const int cell = blockIdx.x;
    const int b = blockIdx.y;
    const int cy = cell >> 5, cx = cell & 31;

    const int py = (cy << 4) + (t >> 4);
    const int px = (cx << 4) + (t & 15);
    const float* xp = x + (size_t)b * (NC * HW) + (size_t)py * NW + px;
    float xv[NC];
#pragma unroll
    for (int c = 0; c < NC; ++c) xv[c] = xp[(size_t)c * HW];

    if (t < 180) {
        const int o = t / 20, c = t - o * 20;
        const int ny = clampi(cy + c_dyo[o], 0, 31);
        const int nx = clampi(cx + c_dxo[o], 0, 31);
        s_lds[o][c] = seeds[((size_t)(b << 10) + (ny << 5) + nx) * NC + c];
    }
    __syncthreads();
    if (t < 9) {
        float s = 0.f;
#pragma unroll
        for (int c = 0; c < NC; ++c) s += s_lds[t][c] * s_lds[t][c];
        s_sn[t] = s;
    }
    __syncthreads();

    float d[9];
#pragma unroll
    for (int o = 0; o < 9; ++o) {
        float ip = 0.f;
#pragma unroll
        for (int j = 0; j < 5; ++j) {
            const float4 s4 = *reinterpret_cast<const float4*>(&s_lds[o][j << 2]);
            ip += xv[(j << 2) + 0] * s4.x + xv[(j << 2) + 1] * s4.y
                + xv[(j << 2) + 2] * s4.z + xv[(j << 2) + 3] * s4.w;
        }
        d[o] = s_sn[o] - 2.0f * ip;
    }
    float m = d[0];
#pragma unroll
    for (int o = 1; o < 9; ++o) m = fminf(m, d[o]);
    float w[9];
    float wsum = 0.f;
#pragma unroll
    for (int o = 0; o < 9; ++o) {
        w[o] = __expf(m - d[o]);
        wsum += w[o];
    }
    const float inv = 1.0f / wsum;
#pragma unroll
    for (int o = 0; o < 9; ++o) {
        out[(((size_t)b * 9 + o) * NH + py) * NW + px] = w[o] * inv;
    }
}

// ---------------------------------------------------------------------------
extern "C" void kernel_launch(void* const* d_in, const int* in_sizes, int n_in,
                              void* d_out, int out_size, void* d_ws, size_t ws_size,
                              hipStream_t stream) {
    const float* x = (const float*)d_in[0];
    float* out = (float*)d_out;

    float* seeds = (float*)d_ws;                 // 163840 floats
    float* numer = seeds + SEEDS_ELEMS;          // 163840 floats
    float* denom = numer + SEEDS_ELEMS;          // 8192 floats

    const dim3 grid(NS, NB);  // 1024 cells x 8 batches
    k_seed_init<<<grid, 160, 0, stream>>>(x, seeds);

    for (int it = 0; it < 3; ++it) {
        hipMemsetAsync(numer, 0, (SEEDS_ELEMS + DENOM_ELEMS) * sizeof(float), stream);
        k_iter<<<grid, 256, 0, stream>>>(x, seeds, numer, denom);
        k_div<<<SEEDS_ELEMS / 256, 256, 0, stream>>>(seeds, numer, denom);
    }
    k_final<<<grid, 256, 0, stream>>>(x, seeds, out);
}